// Round 8
// baseline (639.090 us; speedup 1.0000x reference)
//
#include <hip/hip_runtime.h>

#define NN 65536
#define EE 262144
#define ND ((size_t)NN * 128)
#define TBW 132

typedef unsigned short u16;
typedef short bf8_t __attribute__((ext_vector_type(8)));
typedef float f32x4 __attribute__((ext_vector_type(4)));

__device__ __forceinline__ float lrelu(float x){ return x > 0.f ? x : 0.2f*x; }
__device__ __forceinline__ float gelu_exact(float x){ return 0.5f*x*(1.f+erff(x*0.70710678118654752f)); }
__device__ __forceinline__ u16 f2bf(float f){
    union { float f; unsigned u; } v; v.f = f;
    unsigned u = v.u;
    return (u16)((u + 0x7FFFu + ((u >> 16) & 1u)) >> 16);
}
__device__ __forceinline__ float bf2f(u16 b){
    union { unsigned u; float f; } v; v.u = ((unsigned)b) << 16; return v.f;
}
__device__ __forceinline__ float2 bf2x(unsigned p){
    union { unsigned u; float f; } a, b;
    a.u = (p & 0xFFFFu) << 16; b.u = p & 0xFFFF0000u;
    return make_float2(a.f, b.f);
}
__device__ __forceinline__ unsigned cvt2(float a, float b){
    unsigned r; asm("v_cvt_pk_bf16_f32 %0, %1, %2" : "=v"(r) : "v"(a), "v"(b)); return r;
}

// ============ register-GEMM building blocks (no barriers) ============
__device__ __forceinline__ void load_af32(const float* __restrict__ X, int row, int lk, bf8_t* af){
    #pragma unroll
    for (int kk = 0; kk < 4; ++kk){
        const float* p = X + (size_t)row*128 + kk*32 + lk*8;
        float4 a = *(const float4*)p;
        float4 b = *(const float4*)(p+4);
        union { bf8_t v; unsigned u[4]; } r;
        r.u[0] = cvt2(a.x, a.y); r.u[1] = cvt2(a.z, a.w);
        r.u[2] = cvt2(b.x, b.y); r.u[3] = cvt2(b.z, b.w);
        af[kk] = r.v;
    }
}
__device__ __forceinline__ void load_af16(const u16* __restrict__ X, int row, int lk, bf8_t* af){
    #pragma unroll
    for (int kk = 0; kk < 4; ++kk)
        af[kk] = *(const bf8_t*)(X + (size_t)row*128 + kk*32 + lk*8);
}
__device__ __forceinline__ void mfma_w1_acc(const bf8_t* af, const u16* __restrict__ Wp,
                                            int lr, int lk, f32x4* acc){
    #pragma unroll
    for (int kk = 0; kk < 4; ++kk){
        bf8_t B[8];
        #pragma unroll
        for (int nt = 0; nt < 8; ++nt)
            B[nt] = *(const bf8_t*)&Wp[(nt*16+lr)*128 + kk*32 + lk*8];
        #pragma unroll
        for (int nt = 0; nt < 8; ++nt)
            acc[nt] = __builtin_amdgcn_mfma_f32_16x16x32_bf16(af[kk], B[nt], acc[nt], 0, 0, 0);
    }
}
__device__ __forceinline__ void mfma_w1(const bf8_t* af, const u16* __restrict__ Wp,
                                        int lr, int lk, f32x4* acc){
    #pragma unroll
    for (int i = 0; i < 8; ++i) acc[i] = (f32x4){0.f,0.f,0.f,0.f};
    mfma_w1_acc(af, Wp, lr, lk, acc);
}
__device__ __forceinline__ void mfma_w2_acc(const bf8_t* af0, const bf8_t* af1,
                                            const u16* __restrict__ Wp,
                                            int lr, int lk, f32x4* acc0, f32x4* acc1){
    #pragma unroll
    for (int kk = 0; kk < 4; ++kk){
        bf8_t B[8];
        #pragma unroll
        for (int nt = 0; nt < 8; ++nt)
            B[nt] = *(const bf8_t*)&Wp[(nt*16+lr)*128 + kk*32 + lk*8];
        #pragma unroll
        for (int nt = 0; nt < 8; ++nt){
            acc0[nt] = __builtin_amdgcn_mfma_f32_16x16x32_bf16(af0[kk], B[nt], acc0[nt], 0, 0, 0);
            acc1[nt] = __builtin_amdgcn_mfma_f32_16x16x32_bf16(af1[kk], B[nt], acc1[nt], 0, 0, 0);
        }
    }
}
__device__ __forceinline__ void mfma_w2(const bf8_t* af0, const bf8_t* af1,
                                        const u16* __restrict__ Wp,
                                        int lr, int lk, f32x4* acc0, f32x4* acc1){
    #pragma unroll
    for (int i = 0; i < 8; ++i){ acc0[i] = (f32x4){0.f,0.f,0.f,0.f}; acc1[i] = (f32x4){0.f,0.f,0.f,0.f}; }
    mfma_w2_acc(af0, af1, Wp, lr, lk, acc0, acc1);
}
__device__ __forceinline__ void acc_to_tb(u16 (*tbw)[TBW], const f32x4* acc, int lr, int lk, const float* bias){
    asm volatile("s_waitcnt lgkmcnt(0)" ::: "memory");   // WAR: prior tb reads done
    #pragma unroll
    for (int nt = 0; nt < 8; ++nt){
        int col = nt*16 + lr;
        float badd = bias ? bias[col] : 0.f;
        #pragma unroll
        for (int i = 0; i < 4; ++i) tbw[lk*4+i][col] = f2bf(acc[nt][i] + badd);
    }
    asm volatile("s_waitcnt lgkmcnt(0)" ::: "memory");   // RAW: writes visible
}
__device__ __forceinline__ void acc_to_tb_gelu(u16 (*tbw)[TBW], const f32x4* acc, int lr, int lk){
    asm volatile("s_waitcnt lgkmcnt(0)" ::: "memory");
    #pragma unroll
    for (int nt = 0; nt < 8; ++nt){
        int col = nt*16 + lr;
        #pragma unroll
        for (int i = 0; i < 4; ++i) tbw[lk*4+i][col] = f2bf(gelu_exact(acc[nt][i]));
    }
    asm volatile("s_waitcnt lgkmcnt(0)" ::: "memory");
}
__device__ __forceinline__ void tb_store(const u16 (*tbw)[TBW], u16* __restrict__ O, size_t rowstride, int rowbase, int lr, int lk){
    #pragma unroll
    for (int c = 0; c < 4; ++c){
        bf8_t v = *(const bf8_t*)&tbw[c*4+lk][lr*8];
        *(bf8_t*)(O + (size_t)(rowbase + c*4 + lk)*rowstride + lr*8) = v;
    }
}
__device__ __forceinline__ void tb_frags(const u16 (*tbw)[TBW], int lr, int lk, bf8_t* ha){
    #pragma unroll
    for (int kk = 0; kk < 4; ++kk) ha[kk] = *(const bf8_t*)&tbw[lr][kk*32 + lk*8];
}
// row-major readback: lane gets rows c*4+lk (c=0..3), cols lr*8..+7
__device__ __forceinline__ void tb_rows(const u16 (*tbw)[TBW], int lr, int lk, bf8_t* rw){
    #pragma unroll
    for (int c = 0; c < 4; ++c) rw[c] = *(const bf8_t*)&tbw[c*4+lk][lr*8];
}

// ============ weight pre-pack: f32 -> bf16, B-frag layout ============
__global__ __launch_bounds__(256) void wpack_k(
    const float* __restrict__ g1W, const float* __restrict__ g2W,
    const float* __restrict__ Wk, const float* __restrict__ Wq, const float* __restrict__ Wv,
    const float* __restrict__ Wo, const float* __restrict__ injW,
    const float* __restrict__ arel, const float* __restrict__ mrel,
    const float* __restrict__ g1as, const float* __restrict__ g1ad,
    const float* __restrict__ g2as, const float* __restrict__ g2ad,
    u16* __restrict__ wp, u16* __restrict__ wpa)
{
    int b = blockIdx.x, tid = threadIdx.x;
    if (b < 17) {
        const float* src; int rel = 0;  // 0: plain, 1: blockdiag std, 2: blockdiag transposed
        if (b < 3) src = g1W + b*16384;
        else if (b < 6) src = g2W + (b-3)*16384;
        else if (b == 6) src = Wk;
        else if (b == 7) src = Wq;
        else if (b == 8) src = Wv;
        else if (b == 9) src = Wo;
        else if (b == 10) src = injW;
        else if (b < 14) { src = arel + (b-11)*4096; rel = 2; }
        else { src = mrel + (b-14)*4096; rel = 1; }
        u16* dst = wp + (size_t)b*16384;
        for (int idx = tid; idx < 16384; idx += 256) {
            int n = idx >> 7, k = idx & 127;
            float v;
            if (rel == 1)      v = ((n>>5)==(k>>5)) ? src[(n>>5)*1024 + (k&31)*32 + (n&31)] : 0.f;
            else if (rel == 2) v = ((n>>5)==(k>>5)) ? src[(n>>5)*1024 + (n&31)*32 + (k&31)] : 0.f;
            else               v = src[k*128 + n];
            dst[idx] = f2bf(v);
        }
    } else {
        for (int idx = tid; idx < 6*2048; idx += 256) {
            int m = idx >> 11;
            int j = idx & 2047;
            int cg = j >> 7, k = j & 127;
            const float* as = (m < 3) ? g1as : g2as;
            const float* ad = (m < 3) ? g1ad : g2ad;
            int t = (m < 3) ? m : m - 3;
            float v = 0.f;
            if (cg < 4)      { if ((k>>5)==cg)   v = as[t*128 + cg*32 + (k&31)]; }
            else if (cg < 8) { int g = cg-4; if ((k>>5)==g) v = ad[t*128 + g*32 + (k&31)]; }
            wpa[idx] = f2bf(v);
        }
    }
}

// ============ GAT: 3 projections + fused alpha (via MFMA), bf16 h out, 2 tiles/wave ============
template<int AF32>
__global__ __launch_bounds__(256, 2) void gat_gemm3_k(const float* __restrict__ Xf, const u16* __restrict__ Xb,
    const u16* __restrict__ wpg, const u16* __restrict__ wpa,
    u16* __restrict__ hb, float* __restrict__ alsb, float* __restrict__ aldb)
{
    __shared__ u16 tb[4][16][TBW];
    const int tid = threadIdx.x, wave = tid>>6, lane = tid&63, lr = lane&15, lk = lane>>4;
    const int rw0 = blockIdx.x*128 + wave*32;
    bf8_t af0[4], af1[4];
    if (AF32){ load_af32(Xf, rw0 + lr, lk, af0); load_af32(Xf, rw0 + 16 + lr, lk, af1); }
    else     { load_af16(Xb, rw0 + lr, lk, af0); load_af16(Xb, rw0 + 16 + lr, lk, af1); }
    f32x4 acc0[8], acc1[8];
    for (int t = 0; t < 3; ++t) {
        mfma_w2(af0, af1, wpg + t*16384, lr, lk, acc0, acc1);
        bf8_t Ba[4];
        #pragma unroll
        for (int kk = 0; kk < 4; ++kk)
            Ba[kk] = *(const bf8_t*)&wpa[t*2048 + lr*128 + kk*32 + lk*8];
        u16* h = hb + (size_t)t*ND;
        float* alst = alsb + (size_t)t*NN*4;
        float* aldt = aldb + (size_t)t*NN*4;
        // ---- tile 0 ----
        {
            acc_to_tb(tb[wave], acc0, lr, lk, nullptr);
            tb_store(tb[wave], h, 128, rw0, lr, lk);
            bf8_t ha[4]; tb_frags(tb[wave], lr, lk, ha);
            f32x4 a2 = (f32x4){0.f,0.f,0.f,0.f};
            #pragma unroll
            for (int kk = 0; kk < 4; ++kk)
                a2 = __builtin_amdgcn_mfma_f32_16x16x32_bf16(ha[kk], Ba[kk], a2, 0, 0, 0);
            if (lr < 8){
                float* dp = (lr < 4) ? alst : aldt;
                int g = lr & 3;
                #pragma unroll
                for (int i = 0; i < 4; ++i) dp[(size_t)(rw0 + lk*4 + i)*4 + g] = a2[i];
            }
        }
        // ---- tile 1 ----
        {
            acc_to_tb(tb[wave], acc1, lr, lk, nullptr);
            tb_store(tb[wave], h, 128, rw0 + 16, lr, lk);
            bf8_t ha[4]; tb_frags(tb[wave], lr, lk, ha);
            f32x4 a2 = (f32x4){0.f,0.f,0.f,0.f};
            #pragma unroll
            for (int kk = 0; kk < 4; ++kk)
                a2 = __builtin_amdgcn_mfma_f32_16x16x32_bf16(ha[kk], Ba[kk], a2, 0, 0, 0);
            if (lr < 8){
                float* dp = (lr < 4) ? alst : aldt;
                int g = lr & 3;
                #pragma unroll
                for (int i = 0; i < 4; ++i) dp[(size_t)(rw0 + 16 + lk*4 + i)*4 + g] = a2[i];
            }
        }
    }
}

// ============ HGT projections: kv (k|v interleaved, bias folded) + qt_t = q @ A_t^T ============
__global__ __launch_bounds__(256, 2) void hgt_proj_k(const u16* __restrict__ X,
    const u16* __restrict__ wpk, const u16* __restrict__ wpq, const u16* __restrict__ wpv,
    const u16* __restrict__ wparel,
    const float* __restrict__ bk, const float* __restrict__ bq, const float* __restrict__ bv,
    u16* __restrict__ kvb, u16* __restrict__ qtb)
{
    __shared__ u16 tb[4][16][TBW];
    const int tid = threadIdx.x, wave = tid>>6, lane = tid&63, lr = lane&15, lk = lane>>4;
    const int rw0 = blockIdx.x*128 + wave*32;
    bf8_t af0[4], af1[4];
    load_af16(X, rw0 + lr, lk, af0);
    load_af16(X, rw0 + 16 + lr, lk, af1);
    f32x4 acc0[8], acc1[8];
    // k -> kv[:,0:128]
    mfma_w2(af0, af1, wpk, lr, lk, acc0, acc1);
    acc_to_tb(tb[wave], acc0, lr, lk, bk); tb_store(tb[wave], kvb, 256, rw0, lr, lk);
    acc_to_tb(tb[wave], acc1, lr, lk, bk); tb_store(tb[wave], kvb, 256, rw0 + 16, lr, lk);
    // v -> kv[:,128:256]
    mfma_w2(af0, af1, wpv, lr, lk, acc0, acc1);
    acc_to_tb(tb[wave], acc0, lr, lk, bv); tb_store(tb[wave], kvb + 128, 256, rw0, lr, lk);
    acc_to_tb(tb[wave], acc1, lr, lk, bv); tb_store(tb[wave], kvb + 128, 256, rw0 + 16, lr, lk);
    // q (not stored) -> frags
    bf8_t ha0[4], ha1[4];
    mfma_w2(af0, af1, wpq, lr, lk, acc0, acc1);
    acc_to_tb(tb[wave], acc0, lr, lk, bq); tb_frags(tb[wave], lr, lk, ha0);
    acc_to_tb(tb[wave], acc1, lr, lk, bq); tb_frags(tb[wave], lr, lk, ha1);
    // qt_t = q @ A_t^T
    for (int t = 0; t < 3; ++t){
        mfma_w2(ha0, ha1, wparel + t*16384, lr, lk, acc0, acc1);
        u16* o = qtb + (size_t)t*ND;
        acc_to_tb(tb[wave], acc0, lr, lk, nullptr); tb_store(tb[wave], o, 128, rw0, lr, lk);
        acc_to_tb(tb[wave], acc1, lr, lk, nullptr); tb_store(tb[wave], o, 128, rw0 + 16, lr, lk);
    }
}

// ============ HGT aggregate: 4-edge chunked gather of kv[src], joint softmax, per-type partials ============
__global__ __launch_bounds__(256) void hgt_agg_k(const u16* __restrict__ kvb,
    const u16* __restrict__ qtb, const float* __restrict__ prel,
    const int* __restrict__ coff, const int* __restrict__ csrc,
    u16* __restrict__ pb)
{
    int gid = blockIdx.x*256 + threadIdx.x;
    int node = gid >> 6, lane = gid & 63;
    int hh = lane >> 4;
    float a0[3], a1[3];
    float dsum = 0.f;
    #pragma unroll
    for (int t = 0; t < 3; ++t) {
        a0[t] = 0.f; a1[t] = 0.f;
        float ph = prel[t*4 + hh] * 0.17677669529663689f;  // 1/sqrt(32)
        float2 qv = bf2x(*(const unsigned*)&qtb[(size_t)t*ND + (size_t)node*128 + lane*2]);
        const int* cs = csrc + (size_t)t*EE;
        int beg = coff[t*(NN+1) + node], end = coff[t*(NN+1) + node + 1];
        int e = beg;
        for (; e + 4 <= end; e += 4) {
            int sA = cs[e], sB = cs[e+1], sC = cs[e+2], sD = cs[e+3];
            size_t rA = (size_t)sA*256 + lane*2, rB = (size_t)sB*256 + lane*2;
            size_t rC = (size_t)sC*256 + lane*2, rD = (size_t)sD*256 + lane*2;
            unsigned kA = *(const unsigned*)&kvb[rA], kB = *(const unsigned*)&kvb[rB];
            unsigned kC = *(const unsigned*)&kvb[rC], kD = *(const unsigned*)&kvb[rD];
            unsigned vA = *(const unsigned*)&kvb[rA+128], vB = *(const unsigned*)&kvb[rB+128];
            unsigned vC = *(const unsigned*)&kvb[rC+128], vD = *(const unsigned*)&kvb[rD+128];
            float2 k2A = bf2x(kA), k2B = bf2x(kB), k2C = bf2x(kC), k2D = bf2x(kD);
            float scA = qv.x*k2A.x + qv.y*k2A.y;
            float scB = qv.x*k2B.x + qv.y*k2B.y;
            float scC = qv.x*k2C.x + qv.y*k2C.y;
            float scD = qv.x*k2D.x + qv.y*k2D.y;
            #pragma unroll
            for (int o = 1; o < 16; o <<= 1){
                scA += __shfl_xor(scA, o); scB += __shfl_xor(scB, o);
                scC += __shfl_xor(scC, o); scD += __shfl_xor(scD, o);
            }
            float eA = expf(scA*ph), eB = expf(scB*ph), eC = expf(scC*ph), eD = expf(scD*ph);
            float2 v2A = bf2x(vA), v2B = bf2x(vB), v2C = bf2x(vC), v2D = bf2x(vD);
            dsum += eA + eB + eC + eD;
            a0[t] += eA*v2A.x + eB*v2B.x + eC*v2C.x + eD*v2D.x;
            a1[t] += eA*v2A.y + eB*v2B.y + eC*v2C.y + eD*v2D.y;
        }
        for (; e < end; ++e) {
            int s = cs[e];
            size_t ro = (size_t)s*256 + lane*2;
            float2 kv = bf2x(*(const unsigned*)&kvb[ro]);
            float sc = qv.x*kv.x + qv.y*kv.y;
            #pragma unroll
            for (int o = 1; o < 16; o <<= 1) sc += __shfl_xor(sc, o);
            float ex = expf(sc * ph);
            float2 vx = bf2x(*(const unsigned*)&kvb[ro + 128]);
            dsum += ex; a0[t] += ex*vx.x; a1[t] += ex*vx.y;
        }
    }
    float inv = 1.f/(dsum + 1e-16f);
    size_t o = (size_t)node*128 + lane*2;
    #pragma unroll
    for (int t = 0; t < 3; ++t)
        *(unsigned*)&pb[(size_t)t*ND + o] = cvt2(a0[t]*inv, a1[t]*inv);
}

// ============ final: Σ_t partial_t@M_t, gelu, @Wo + residual/rmsnorm + inject + FiLM ============
// 2-tile, fully vectorized row-major epilogue via the LDS transpose buffer.
__global__ __launch_bounds__(256, 2) void final_k(const u16* __restrict__ pb,
    const u16* __restrict__ wpmrel, const u16* __restrict__ wpo, const float* __restrict__ bo,
    const u16* __restrict__ x2b, const float* __restrict__ skipp, const float* __restrict__ scale,
    const float* __restrict__ xemb, const u16* __restrict__ wpinj, const float* __restrict__ injb,
    const float* __restrict__ gbuf, const int* __restrict__ bszp,
    float* __restrict__ out)
{
    __shared__ u16 tb[4][2][16][TBW];
    const int tid = threadIdx.x, wave = tid>>6, lane = tid&63, lr = lane&15, lk = lane>>4;
    const int rw0 = blockIdx.x*128 + wave*32;
    const int rw1 = rw0 + 16;
    // ---- agg_pre = Σ_t partial_t @ M_t (2 tiles, shared B) ----
    f32x4 acc0[8], acc1[8];
    #pragma unroll
    for (int i = 0; i < 8; ++i){ acc0[i] = (f32x4){0.f,0.f,0.f,0.f}; acc1[i] = (f32x4){0.f,0.f,0.f,0.f}; }
    for (int t = 0; t < 3; ++t){
        bf8_t a0[4], a1[4];
        load_af16(pb + (size_t)t*ND, rw0 + lr, lk, a0);
        load_af16(pb + (size_t)t*ND, rw1 + lr, lk, a1);
        mfma_w2_acc(a0, a1, wpmrel + t*16384, lr, lk, acc0, acc1);
    }
    // ---- gelu -> tb -> bf16 A-frags ----
    acc_to_tb_gelu(tb[wave][0], acc0, lr, lk);
    acc_to_tb_gelu(tb[wave][1], acc1, lr, lk);
    bf8_t ga0[4], ga1[4];
    tb_frags(tb[wave][0], lr, lk, ga0);
    tb_frags(tb[wave][1], lr, lk, ga1);
    // ---- Wo GEMM (2 tiles, shared B) ----
    mfma_w2(ga0, ga1, wpo, lr, lk, acc0, acc1);
    // ---- Wo result (+bo) -> tb -> row-major regs ----
    acc_to_tb(tb[wave][0], acc0, lr, lk, bo);
    acc_to_tb(tb[wave][1], acc1, lr, lk, bo);
    bf8_t hw0[4], hw1[4];
    tb_rows(tb[wave][0], lr, lk, hw0);
    tb_rows(tb[wave][1], lr, lk, hw1);
    // ---- inject GEMM (2 tiles, shared B) -> (+injb) -> tb -> row-major regs ----
    bf8_t e0[4], e1[4];
    load_af32(xemb, rw0 + lr, lk, e0);
    load_af32(xemb, rw1 + lr, lk, e1);
    mfma_w2(e0, e1, wpinj, lr, lk, acc0, acc1);
    acc_to_tb(tb[wave][0], acc0, lr, lk, injb);
    acc_to_tb(tb[wave][1], acc1, lr, lk, injb);
    bf8_t in0[4], in1[4];
    tb_rows(tb[wave][0], lr, lk, in0);
    tb_rows(tb[wave][1], lr, lk, in1);
    // ---- vectorized row-major epilogue ----
    const float sig = 1.f/(1.f + expf(-skipp[0]));
    const int cpb = NN / *bszp;
    float4 sca = *(const float4*)&scale[lr*8];
    float4 scb = *(const float4*)&scale[lr*8 + 4];
    #pragma unroll
    for (int tile = 0; tile < 2; ++tile){
        const bf8_t* hw = tile ? hw1 : hw0;
        const bf8_t* in = tile ? in1 : in0;
        int rwb = tile ? rw1 : rw0;
        #pragma unroll
        for (int c = 0; c < 4; ++c){
            int row = rwb + c*4 + lk;
            bf8_t x8 = *(const bf8_t*)(x2b + (size_t)row*128 + lr*8);
            float x[8], v[8];
            float ssl = 0.f;
            #pragma unroll
            for (int j = 0; j < 8; ++j){
                x[j] = bf2f((u16)x8[j]);
                float h = bf2f((u16)hw[c][j]);
                v[j] = sig*h + (1.f - sig)*x[j];
                ssl += v[j]*v[j];
            }
            ssl += __shfl_xor(ssl, 1); ssl += __shfl_xor(ssl, 2);
            ssl += __shfl_xor(ssl, 4); ssl += __shfl_xor(ssl, 8);
            float rq = rsqrtf(ssl*(1.f/128.f) + 1e-6f);
            const float* gr = gbuf + (row / cpb)*256;
            float4 g0 = *(const float4*)&gr[lr*8];
            float4 g1 = *(const float4*)&gr[lr*8 + 4];
            float4 b0 = *(const float4*)&gr[128 + lr*8];
            float4 b1 = *(const float4*)&gr[128 + lr*8 + 4];
            float4 oA, oB;
            #pragma unroll
            for (int j = 0; j < 8; ++j){
                float scj = (j < 4) ? ((const float*)&sca)[j] : ((const float*)&scb)[j-4];
                float y = lrelu(x[j] + scj*v[j]*rq);
                float hf = y + bf2f((u16)in[c][j]);
                float gj = (j < 4) ? ((const float*)&g0)[j] : ((const float*)&g1)[j-4];
                float bj = (j < 4) ? ((const float*)&b0)[j] : ((const float*)&b1)[j-4];
                float ov = (1.f + gj)*hf + bj;
                if (j < 4) ((float*)&oA)[j] = ov; else ((float*)&oB)[j-4] = ov;
            }
            *(float4*)(out + (size_t)row*128 + lr*8)     = oA;
            *(float4*)(out + (size_t)row*128 + lr*8 + 4) = oB;
        }
    }
}

// ================= CSR build =================
__global__ __launch_bounds__(256) void hist_k(const int* __restrict__ ei, int* __restrict__ cnt){
    int gid = blockIdx.x*256 + threadIdx.x;
    int t = gid / EE, e = gid - t*EE;
    int d = ei[t*2*EE + EE + e];
    atomicAdd(&cnt[t*NN + d], 1);
}
__global__ __launch_bounds__(256) void scan1_k(const int* __restrict__ cnt, int* __restrict__ off, int* __restrict__ parts){
    __shared__ int sums[256];
    int b = blockIdx.x; int t = b >> 6; int base = (b & 63) * 1024;
    int tid = threadIdx.x;
    int v[4]; int tsum = 0;
    int gbase = t*NN + base + tid*4;
    #pragma unroll
    for (int i = 0; i < 4; ++i){ v[i] = cnt[gbase+i]; tsum += v[i]; }
    sums[tid] = tsum; __syncthreads();
    for (int ofs = 1; ofs < 256; ofs <<= 1) {
        int a = (tid >= ofs) ? sums[tid-ofs] : 0;
        __syncthreads();
        sums[tid] += a;
        __syncthreads();
    }
    int run = sums[tid] - tsum;
    int obase = t*(NN+1) + base + tid*4;
    #pragma unroll
    for (int i = 0; i < 4; ++i){ off[obase+i] = run; run += v[i]; }
    if (tid == 255) parts[b] = sums[255];
}
__global__ void scan2_k(int* parts){
    if (threadIdx.x == 0 && blockIdx.x == 0) {
        for (int t = 0; t < 3; ++t) {
            int run = 0;
            for (int i = 0; i < 64; ++i) { int b = t*64+i; int v = parts[b]; parts[b] = run; run += v; }
        }
    }
}
__global__ __launch_bounds__(256) void scan3_k(int* __restrict__ off, const int* __restrict__ parts){
    int b = blockIdx.x; int t = b >> 6; int base = (b & 63) * 1024;
    int add = parts[b];
    int idx = t*(NN+1) + base + threadIdx.x*4;
    #pragma unroll
    for (int i = 0; i < 4; ++i) off[idx+i] += add;
    if (threadIdx.x == 0 && (b & 63) == 0) off[t*(NN+1) + NN] = EE;
}
__global__ __launch_bounds__(256) void scatter_k(const int* __restrict__ ei, const int* __restrict__ off,
                                                 int* __restrict__ cur, int* __restrict__ out){
    int gid = blockIdx.x*256 + threadIdx.x;
    int t = gid / EE, e = gid - t*EE;
    int s = ei[t*2*EE + e];
    int d = ei[t*2*EE + EE + e];
    int p = atomicAdd(&cur[t*NN + d], 1);
    out[t*EE + off[t*(NN+1)+d] + p] = s;
}

// ============ fused GAT aggregate (4-edge chunked bf16 h gather) + bias + rmsnorm residual ============
template<int XF32>
__global__ __launch_bounds__(256) void gat_aggres_k(const u16* __restrict__ hb,
    const float* __restrict__ alsb, const float* __restrict__ aldb,
    const int* __restrict__ coff, const int* __restrict__ csrc,
    const float* __restrict__ bias3, const float* __restrict__ xoldf, const u16* __restrict__ xoldb,
    const float* __restrict__ scale, u16* __restrict__ outb)
{
    int gid = blockIdx.x*256 + threadIdx.x;
    int node = gid >> 6, lane = gid & 63;
    int g = lane >> 4;
    float a0 = 0.f, a1 = 0.f;
    for (int t = 0; t < 3; ++t) {
        const u16* h = hb + (size_t)t*ND;
        const float* als = alsb + (size_t)t*NN*4;
        float ad = aldb[(size_t)t*NN*4 + node*4 + g];
        float aself = als[node*4 + g];
        const int* cs = csrc + (size_t)t*EE;
        int beg = coff[t*(NN+1) + node], end = coff[t*(NN+1) + node + 1];
        float ex = expf(lrelu(aself + ad));
        float dsum = ex;
        float2 hv = bf2x(*(const unsigned*)&h[(size_t)node*128 + lane*2]);
        float s0 = ex*hv.x, s1 = ex*hv.y;
        int e = beg;
        for (; e + 4 <= end; e += 4) {
            int sA = cs[e], sB = cs[e+1], sC = cs[e+2], sD = cs[e+3];
            unsigned hA = *(const unsigned*)&h[(size_t)sA*128 + lane*2];
            unsigned hB = *(const unsigned*)&h[(size_t)sB*128 + lane*2];
            unsigned hC = *(const unsigned*)&h[(size_t)sC*128 + lane*2];
            unsigned hD = *(const unsigned*)&h[(size_t)sD*128 + lane*2];
            float aA = als[sA*4+g], aB = als[sB*4+g], aC = als[sC*4+g], aD = als[sD*4+g];
            float eA = expf(lrelu(aA + ad)), eB = expf(lrelu(aB + ad));
            float eC = expf(lrelu(aC + ad)), eD = expf(lrelu(aD + ad));
            float2 wA = bf2x(hA), wB = bf2x(hB), wC = bf2x(hC), wD = bf2x(hD);
            dsum += eA + eB + eC + eD;
            s0 += eA*wA.x + eB*wB.x + eC*wC.x + eD*wD.x;
            s1 += eA*wA.y + eB*wB.y + eC*wC.y + eD*wD.y;
        }
        for (; e < end; ++e) {
            int s = cs[e];
            unsigned hp = *(const unsigned*)&h[(size_t)s*128 + lane*2];
            float av = als[s*4 + g];
            float exx = expf(lrelu(av + ad));
            float2 hw = bf2x(hp);
            dsum += exx; s0 += exx*hw.x; s1 += exx*hw.y;
        }
        float inv = 1.f/(dsum + 1e-16f);
        a0 += s0*inv; a1 += s1*inv;
    }
    int c0 = lane*2;
    a0 += bias3[c0]   + bias3[128+c0]   + bias3[256+c0];
    a1 += bias3[c0+1] + bias3[128+c0+1] + bias3[256+c0+1];
    float ssum = a0*a0 + a1*a1;
    #pragma unroll
    for (int o = 1; o < 64; o <<= 1) ssum += __shfl_xor(ssum, o);
    float r = rsqrtf(ssum*(1.f/128.f) + 1e-6f);
    size_t off = (size_t)node*128 + c0;
    float2 xo;
    if (XF32) xo = *(const float2*)&xoldf[off];
    else      xo = bf2x(*(const unsigned*)&xoldb[off]);
    float y0 = lrelu(xo.x + scale[c0]*a0*r);
    float y1 = lrelu(xo.y + scale[c0+1]*a1*r);
    *(unsigned*)&outb[off] = cvt2(y0, y1);
}

// ============ FiLM small MLP ============
__global__ __launch_bounds__(256) void film_k(const float* __restrict__ z,
    const float* __restrict__ W1, const float* __restrict__ b1,
    const float* __restrict__ W2, const float* __restrict__ b2,
    float* __restrict__ gb)
{
    __shared__ float zr[128];
    __shared__ float g1[256];
    int r = blockIdx.x, tid = threadIdx.x;
    if (tid < 128) zr[tid] = z[r*128 + tid];
    __syncthreads();
    float s = b1[tid];
    for (int k = 0; k < 128; ++k) s += zr[k]*W1[k*256 + tid];
    g1[tid] = gelu_exact(s);
    __syncthreads();
    float s2 = b2[tid];
    for (int k = 0; k < 256; ++k) s2 += g1[k]*W2[k*256 + tid];
    gb[r*256 + tid] = 0.1f*tanhf(s2);
}

// ================= launch =================
extern "C" void kernel_launch(void* const* d_in, const int* in_sizes, int n_in,
                              void* d_out, int out_size, void* d_ws, size_t ws_size,
                              hipStream_t stream)
{
    const float* x_cell = (const float*)d_in[0];
    const float* z_h    = (const float*)d_in[1];
    const float* x_emb  = (const float*)d_in[2];
    const int*   eidx   = (const int*)d_in[3];
    const int*   bszp   = (const int*)d_in[4];
    const float* g1W  = (const float*)d_in[5];
    const float* g1as = (const float*)d_in[6];
    const float* g1ad = (const float*)d_in[7];
    const float* g1b  = (const float*)d_in[8];
    const float* g2W  = (const float*)d_in[9];
    const float* g2as = (const float*)d_in[10];
    const float* g2ad = (const float*)d_in[11];
    const float* g2b  = (const float*)d_in[12];
    const float* n1s  = (const float*)d_in[13];
    const float* n2s  = (const float*)d_in[14];
    const float* n3s  = (const float*)d_in[15];
    const float* Wk   = (const float*)d_in[16];
    const float* bk   = (const float*)d_in[17];
    const float* Wq   = (const float*)d_in[18];
    const float* bq   = (const float*)d_in[19];
    const float* Wv   = (const float*)d_in[20];
    const float* bv   = (const float*)d_in[21];
    const float* arel = (const float*)d_in[22];
    const float* mrel = (const float*)d_in[23];
    const float* prel = (const float*)d_in[24];
    const float* Wo   = (const float*)d_in[25];
    const float* bo   = (const float*)d_in[26];
    const float* skipp= (const float*)d_in[27];
    const float* injW = (const float*)d_in[28];
    const float* injb = (const float*)d_in[29];
    const float* fW1  = (const float*)d_in[30];
    const float* fb1  = (const float*)d_in[31];
    const float* fW2  = (const float*)d_in[32];
    const float* fb2  = (const float*)d_in[33];

    // ---- workspace layout ----
    u16* wp   = (u16*)d_ws;                   // 17*16384 u16
    u16* wpa  = wp + (size_t)17*16384;        // 6*2048 u16
    u16* x1b  = wpa + 6*2048;                 // ND u16
    u16* x2b  = x1b + ND;                     // ND u16
    u16* kvb  = x2b + ND;                     // 2*ND u16 (k|v interleaved, row 256)
    u16* pb   = kvb + 2*ND;                   // 3*ND u16 (HGT per-type partials)
    u16* hb   = pb + 3*ND;                    // 3*ND u16 (GAT h; reused as qtb)
    float* alsb = (float*)(hb + 3*ND);        // 3*NN*4 f32
    float* aldb = alsb + (size_t)3*NN*4;      // 3*NN*4 f32
    float* gbuf = aldb + (size_t)3*NN*4;      // 32*256 f32
    int* coff   = (int*)(gbuf + 32*256);      // 3*(NN+1)
    int* csrc   = coff + 3*(NN+1);            // 3*EE
    int* tmpc   = csrc + 3*EE;                // 3*NN
    int* parts  = tmpc + 3*NN;                // 256

    u16* qtb = hb;                            // reuse (h dead after GAT2 aggres)
    float* outp = (float*)d_out;

    const u16* wpg1 = wp;
    const u16* wpg2 = wp + (size_t)3*16384;
    const u16* wpk  = wp + (size_t)6*16384;
    const u16* wpq  = wp + (size_t)7*16384;
    const u16* wpv  = wp + (size_t)8*16384;
    const u16* wpo  = wp + (size_t)9*16384;
    const u16* wpinj= wp + (size_t)10*16384;
    const u16* wparel = wp + (size_t)11*16384;
    const u16* wpmrel = wp + (size_t)14*16384;

    // ---- weight pre-pack ----
    wpack_k<<<18, 256, 0, stream>>>(g1W, g2W, Wk, Wq, Wv, Wo, injW, arel, mrel,
                                    g1as, g1ad, g2as, g2ad, wp, wpa);

    // ---- CSR build (shared by GAT1, GAT2, HGT) ----
    hipMemsetAsync(tmpc, 0, 3*NN*sizeof(int), stream);
    hist_k<<<3*EE/256, 256, 0, stream>>>(eidx, tmpc);
    scan1_k<<<192, 256, 0, stream>>>(tmpc, coff, parts);
    scan2_k<<<1, 64, 0, stream>>>(parts);
    scan3_k<<<192, 256, 0, stream>>>(coff, parts);
    hipMemsetAsync(tmpc, 0, 3*NN*sizeof(int), stream);
    scatter_k<<<3*EE/256, 256, 0, stream>>>(eidx, coff, tmpc, csrc);

    // ---- FiLM small MLP ----
    int B = in_sizes[1] / 128;
    film_k<<<B, 256, 0, stream>>>(z_h, fW1, fb1, fW2, fb2, gbuf);

    // ---- GAT layer 1 ----
    gat_gemm3_k<1><<<512, 256, 0, stream>>>(x_cell, nullptr, wpg1, wpa, hb, alsb, aldb);
    gat_aggres_k<1><<<16384, 256, 0, stream>>>(hb, alsb, aldb, coff, csrc, g1b, x_cell, nullptr, n1s, x1b);

    // ---- GAT layer 2 ----
    gat_gemm3_k<0><<<512, 256, 0, stream>>>(nullptr, x1b, wpg2, wpa + 3*2048, hb, alsb, aldb);
    gat_aggres_k<0><<<16384, 256, 0, stream>>>(hb, alsb, aldb, coff, csrc, g2b, nullptr, x1b, n2s, x2b);

    // ---- HGT ----
    hgt_proj_k<<<512, 256, 0, stream>>>(x2b, wpk, wpq, wpv, wparel,
                                        bk, bq, bv, kvb, qtb);
    hgt_agg_k<<<16384, 256, 0, stream>>>(kvb, qtb, prel, coff, csrc, pb);

    // ---- final: Σ partial@M + gelu + Wo + residual + inject + FiLM ----
    final_k<<<512, 256, 0, stream>>>(pb, wpmrel, wpo, bo, x2b, skipp, n3s,
                                     x_emb, wpinj, injb, gbuf, bszp, outp);
}

// Round 9
// 572.467 us; speedup vs baseline: 1.1164x; 1.1164x over previous
//
#include <hip/hip_runtime.h>

#define NN 65536
#define EE 262144
#define ND ((size_t)NN * 128)
#define TBW 132
#define WLP 136   // LDS weight pitch (u16) to break bank conflicts

typedef unsigned short u16;
typedef short bf8_t __attribute__((ext_vector_type(8)));
typedef float f32x4 __attribute__((ext_vector_type(4)));

__device__ __forceinline__ float lrelu(float x){ return x > 0.f ? x : 0.2f*x; }
__device__ __forceinline__ float gelu_exact(float x){ return 0.5f*x*(1.f+erff(x*0.70710678118654752f)); }
__device__ __forceinline__ u16 f2bf(float f){
    union { float f; unsigned u; } v; v.f = f;
    unsigned u = v.u;
    return (u16)((u + 0x7FFFu + ((u >> 16) & 1u)) >> 16);
}
__device__ __forceinline__ float bf2f(u16 b){
    union { unsigned u; float f; } v; v.u = ((unsigned)b) << 16; return v.f;
}
__device__ __forceinline__ float2 bf2x(unsigned p){
    union { unsigned u; float f; } a, b;
    a.u = (p & 0xFFFFu) << 16; b.u = p & 0xFFFF0000u;
    return make_float2(a.f, b.f);
}
__device__ __forceinline__ unsigned cvt2(float a, float b){
    unsigned r; asm("v_cvt_pk_bf16_f32 %0, %1, %2" : "=v"(r) : "v"(a), "v"(b)); return r;
}

// ============ A-fragment loads ============
__device__ __forceinline__ void load_af32(const float* __restrict__ X, int row, int lk, bf8_t* af){
    #pragma unroll
    for (int kk = 0; kk < 4; ++kk){
        const float* p = X + (size_t)row*128 + kk*32 + lk*8;
        float4 a = *(const float4*)p;
        float4 b = *(const float4*)(p+4);
        union { bf8_t v; unsigned u[4]; } r;
        r.u[0] = cvt2(a.x, a.y); r.u[1] = cvt2(a.z, a.w);
        r.u[2] = cvt2(b.x, b.y); r.u[3] = cvt2(b.z, b.w);
        af[kk] = r.v;
    }
}
__device__ __forceinline__ void load_af16(const u16* __restrict__ X, int row, int lk, bf8_t* af){
    #pragma unroll
    for (int kk = 0; kk < 4; ++kk)
        af[kk] = *(const bf8_t*)(X + (size_t)row*128 + kk*32 + lk*8);
}

// ============ LDS weight staging (32KB packed -> padded pitch WLP) ============
__device__ __forceinline__ void stage_w(const u16* __restrict__ src, u16* __restrict__ wl, int tid){
    #pragma unroll
    for (int j = 0; j < 8; ++j){
        int o = (j*256 + tid)*8;
        bf8_t v = *(const bf8_t*)(src + o);
        *(bf8_t*)(wl + ((o>>7)*WLP + (o&127))) = v;
    }
}

// ============ MFMA from LDS-staged weights ============
__device__ __forceinline__ void mfma_l1_acc(const bf8_t* af, const u16* __restrict__ wl,
                                            int lr, int lk, f32x4* acc){
    #pragma unroll
    for (int kk = 0; kk < 4; ++kk){
        bf8_t B[8];
        #pragma unroll
        for (int nt = 0; nt < 8; ++nt)
            B[nt] = *(const bf8_t*)&wl[(nt*16+lr)*WLP + kk*32 + lk*8];
        #pragma unroll
        for (int nt = 0; nt < 8; ++nt)
            acc[nt] = __builtin_amdgcn_mfma_f32_16x16x32_bf16(af[kk], B[nt], acc[nt], 0, 0, 0);
    }
}
__device__ __forceinline__ void mfma_l2_acc(const bf8_t* af0, const bf8_t* af1,
                                            const u16* __restrict__ wl,
                                            int lr, int lk, f32x4* acc0, f32x4* acc1){
    #pragma unroll
    for (int kk = 0; kk < 4; ++kk){
        bf8_t B[8];
        #pragma unroll
        for (int nt = 0; nt < 8; ++nt)
            B[nt] = *(const bf8_t*)&wl[(nt*16+lr)*WLP + kk*32 + lk*8];
        #pragma unroll
        for (int nt = 0; nt < 8; ++nt){
            acc0[nt] = __builtin_amdgcn_mfma_f32_16x16x32_bf16(af0[kk], B[nt], acc0[nt], 0, 0, 0);
            acc1[nt] = __builtin_amdgcn_mfma_f32_16x16x32_bf16(af1[kk], B[nt], acc1[nt], 0, 0, 0);
        }
    }
}
__device__ __forceinline__ void mfma_l2(const bf8_t* af0, const bf8_t* af1,
                                        const u16* __restrict__ wl,
                                        int lr, int lk, f32x4* acc0, f32x4* acc1){
    #pragma unroll
    for (int i = 0; i < 8; ++i){ acc0[i] = (f32x4){0.f,0.f,0.f,0.f}; acc1[i] = (f32x4){0.f,0.f,0.f,0.f}; }
    mfma_l2_acc(af0, af1, wl, lr, lk, acc0, acc1);
}

// ============ per-wave LDS transpose buffer ============
__device__ __forceinline__ void acc_to_tb(u16 (*tbw)[TBW], const f32x4* acc, int lr, int lk, const float* bias){
    asm volatile("s_waitcnt lgkmcnt(0)" ::: "memory");   // WAR: prior tb reads done
    #pragma unroll
    for (int nt = 0; nt < 8; ++nt){
        int col = nt*16 + lr;
        float badd = bias ? bias[col] : 0.f;
        #pragma unroll
        for (int i = 0; i < 4; ++i) tbw[lk*4+i][col] = f2bf(acc[nt][i] + badd);
    }
    asm volatile("s_waitcnt lgkmcnt(0)" ::: "memory");   // RAW: writes visible
}
__device__ __forceinline__ void acc_to_tb_gelu(u16 (*tbw)[TBW], const f32x4* acc, int lr, int lk){
    asm volatile("s_waitcnt lgkmcnt(0)" ::: "memory");
    #pragma unroll
    for (int nt = 0; nt < 8; ++nt){
        int col = nt*16 + lr;
        #pragma unroll
        for (int i = 0; i < 4; ++i) tbw[lk*4+i][col] = f2bf(gelu_exact(acc[nt][i]));
    }
    asm volatile("s_waitcnt lgkmcnt(0)" ::: "memory");
}
__device__ __forceinline__ void tb_store(const u16 (*tbw)[TBW], u16* __restrict__ O, size_t rowstride, int rowbase, int lr, int lk){
    #pragma unroll
    for (int c = 0; c < 4; ++c){
        bf8_t v = *(const bf8_t*)&tbw[c*4+lk][lr*8];
        *(bf8_t*)(O + (size_t)(rowbase + c*4 + lk)*rowstride + lr*8) = v;
    }
}
__device__ __forceinline__ void tb_frags(const u16 (*tbw)[TBW], int lr, int lk, bf8_t* ha){
    #pragma unroll
    for (int kk = 0; kk < 4; ++kk) ha[kk] = *(const bf8_t*)&tbw[lr][kk*32 + lk*8];
}
__device__ __forceinline__ void tb_rows(const u16 (*tbw)[TBW], int lr, int lk, bf8_t* rw){
    #pragma unroll
    for (int c = 0; c < 4; ++c) rw[c] = *(const bf8_t*)&tbw[c*4+lk][lr*8];
}

// ============ weight pre-pack: f32 -> bf16, B-frag layout ============
__global__ __launch_bounds__(256) void wpack_k(
    const float* __restrict__ g1W, const float* __restrict__ g2W,
    const float* __restrict__ Wk, const float* __restrict__ Wq, const float* __restrict__ Wv,
    const float* __restrict__ Wo, const float* __restrict__ injW,
    const float* __restrict__ arel, const float* __restrict__ mrel,
    const float* __restrict__ g1as, const float* __restrict__ g1ad,
    const float* __restrict__ g2as, const float* __restrict__ g2ad,
    u16* __restrict__ wp, u16* __restrict__ wpa)
{
    int b = blockIdx.x, tid = threadIdx.x;
    if (b < 17) {
        const float* src; int rel = 0;  // 0: plain, 1: blockdiag std, 2: blockdiag transposed
        if (b < 3) src = g1W + b*16384;
        else if (b < 6) src = g2W + (b-3)*16384;
        else if (b == 6) src = Wk;
        else if (b == 7) src = Wq;
        else if (b == 8) src = Wv;
        else if (b == 9) src = Wo;
        else if (b == 10) src = injW;
        else if (b < 14) { src = arel + (b-11)*4096; rel = 2; }
        else { src = mrel + (b-14)*4096; rel = 1; }
        u16* dst = wp + (size_t)b*16384;
        for (int idx = tid; idx < 16384; idx += 256) {
            int n = idx >> 7, k = idx & 127;
            float v;
            if (rel == 1)      v = ((n>>5)==(k>>5)) ? src[(n>>5)*1024 + (k&31)*32 + (n&31)] : 0.f;
            else if (rel == 2) v = ((n>>5)==(k>>5)) ? src[(n>>5)*1024 + (n&31)*32 + (k&31)] : 0.f;
            else               v = src[k*128 + n];
            dst[idx] = f2bf(v);
        }
    } else {
        for (int idx = tid; idx < 6*2048; idx += 256) {
            int m = idx >> 11;
            int j = idx & 2047;
            int cg = j >> 7, k = j & 127;
            const float* as = (m < 3) ? g1as : g2as;
            const float* ad = (m < 3) ? g1ad : g2ad;
            int t = (m < 3) ? m : m - 3;
            float v = 0.f;
            if (cg < 4)      { if ((k>>5)==cg)   v = as[t*128 + cg*32 + (k&31)]; }
            else if (cg < 8) { int g = cg-4; if ((k>>5)==g) v = ad[t*128 + g*32 + (k&31)]; }
            wpa[idx] = f2bf(v);
        }
    }
}

// ============ GAT: 3 LDS-staged projections + fused alpha, bf16 h out, 2 tiles/wave ============
template<int AF32>
__global__ __launch_bounds__(256, 2) void gat_gemm3_k(const float* __restrict__ Xf, const u16* __restrict__ Xb,
    const u16* __restrict__ wpg, const u16* __restrict__ wpa,
    u16* __restrict__ hb, float* __restrict__ alsb, float* __restrict__ aldb)
{
    __shared__ __align__(16) u16 wl[128*WLP];
    __shared__ __align__(16) u16 tb[4][16][TBW];
    const int tid = threadIdx.x, wave = tid>>6, lane = tid&63, lr = lane&15, lk = lane>>4;
    const int rw0 = blockIdx.x*128 + wave*32;
    bf8_t af0[4], af1[4];
    if (AF32){ load_af32(Xf, rw0 + lr, lk, af0); load_af32(Xf, rw0 + 16 + lr, lk, af1); }
    else     { load_af16(Xb, rw0 + lr, lk, af0); load_af16(Xb, rw0 + 16 + lr, lk, af1); }
    f32x4 acc0[8], acc1[8];
    for (int t = 0; t < 3; ++t) {
        __syncthreads();                       // all waves done with previous weight
        stage_w(wpg + t*16384, wl, tid);
        __syncthreads();                       // staging visible
        mfma_l2(af0, af1, wl, lr, lk, acc0, acc1);
        bf8_t Ba[4];
        #pragma unroll
        for (int kk = 0; kk < 4; ++kk)
            Ba[kk] = *(const bf8_t*)&wpa[t*2048 + lr*128 + kk*32 + lk*8];
        u16* h = hb + (size_t)t*ND;
        float* alst = alsb + (size_t)t*NN*4;
        float* aldt = aldb + (size_t)t*NN*4;
        // ---- tile 0 ----
        {
            acc_to_tb(tb[wave], acc0, lr, lk, nullptr);
            tb_store(tb[wave], h, 128, rw0, lr, lk);
            bf8_t ha[4]; tb_frags(tb[wave], lr, lk, ha);
            f32x4 a2 = (f32x4){0.f,0.f,0.f,0.f};
            #pragma unroll
            for (int kk = 0; kk < 4; ++kk)
                a2 = __builtin_amdgcn_mfma_f32_16x16x32_bf16(ha[kk], Ba[kk], a2, 0, 0, 0);
            if (lr < 8){
                float* dp = (lr < 4) ? alst : aldt;
                int g = lr & 3;
                #pragma unroll
                for (int i = 0; i < 4; ++i) dp[(size_t)(rw0 + lk*4 + i)*4 + g] = a2[i];
            }
        }
        // ---- tile 1 ----
        {
            acc_to_tb(tb[wave], acc1, lr, lk, nullptr);
            tb_store(tb[wave], h, 128, rw0 + 16, lr, lk);
            bf8_t ha[4]; tb_frags(tb[wave], lr, lk, ha);
            f32x4 a2 = (f32x4){0.f,0.f,0.f,0.f};
            #pragma unroll
            for (int kk = 0; kk < 4; ++kk)
                a2 = __builtin_amdgcn_mfma_f32_16x16x32_bf16(ha[kk], Ba[kk], a2, 0, 0, 0);
            if (lr < 8){
                float* dp = (lr < 4) ? alst : aldt;
                int g = lr & 3;
                #pragma unroll
                for (int i = 0; i < 4; ++i) dp[(size_t)(rw0 + 16 + lk*4 + i)*4 + g] = a2[i];
            }
        }
    }
}

// ============ HGT projections: kv (k|v interleaved) + qt_t = q @ A_t^T, LDS-staged weights ============
__global__ __launch_bounds__(256, 2) void hgt_proj_k(const u16* __restrict__ X,
    const u16* __restrict__ wpk, const u16* __restrict__ wpq, const u16* __restrict__ wpv,
    const u16* __restrict__ wparel,
    const float* __restrict__ bk, const float* __restrict__ bq, const float* __restrict__ bv,
    u16* __restrict__ kvb, u16* __restrict__ qtb)
{
    __shared__ __align__(16) u16 wl[128*WLP];
    __shared__ __align__(16) u16 tb[4][16][TBW];
    const int tid = threadIdx.x, wave = tid>>6, lane = tid&63, lr = lane&15, lk = lane>>4;
    const int rw0 = blockIdx.x*128 + wave*32;
    bf8_t af0[4], af1[4];
    load_af16(X, rw0 + lr, lk, af0);
    load_af16(X, rw0 + 16 + lr, lk, af1);
    f32x4 acc0[8], acc1[8];
    // ---- k -> kv[:,0:128] ----
    stage_w(wpk, wl, tid);
    __syncthreads();
    mfma_l2(af0, af1, wl, lr, lk, acc0, acc1);
    acc_to_tb(tb[wave], acc0, lr, lk, bk); tb_store(tb[wave], kvb, 256, rw0, lr, lk);
    acc_to_tb(tb[wave], acc1, lr, lk, bk); tb_store(tb[wave], kvb, 256, rw0 + 16, lr, lk);
    // ---- v -> kv[:,128:256] ----
    __syncthreads();
    stage_w(wpv, wl, tid);
    __syncthreads();
    mfma_l2(af0, af1, wl, lr, lk, acc0, acc1);
    acc_to_tb(tb[wave], acc0, lr, lk, bv); tb_store(tb[wave], kvb + 128, 256, rw0, lr, lk);
    acc_to_tb(tb[wave], acc1, lr, lk, bv); tb_store(tb[wave], kvb + 128, 256, rw0 + 16, lr, lk);
    // ---- q (not stored) -> frags ----
    __syncthreads();
    stage_w(wpq, wl, tid);
    __syncthreads();
    bf8_t ha0[4], ha1[4];
    mfma_l2(af0, af1, wl, lr, lk, acc0, acc1);
    acc_to_tb(tb[wave], acc0, lr, lk, bq); tb_frags(tb[wave], lr, lk, ha0);
    acc_to_tb(tb[wave], acc1, lr, lk, bq); tb_frags(tb[wave], lr, lk, ha1);
    // ---- qt_t = q @ A_t^T ----
    for (int t = 0; t < 3; ++t){
        __syncthreads();
        stage_w(wparel + t*16384, wl, tid);
        __syncthreads();
        mfma_l2(ha0, ha1, wl, lr, lk, acc0, acc1);
        u16* o = qtb + (size_t)t*ND;
        acc_to_tb(tb[wave], acc0, lr, lk, nullptr); tb_store(tb[wave], o, 128, rw0, lr, lk);
        acc_to_tb(tb[wave], acc1, lr, lk, nullptr); tb_store(tb[wave], o, 128, rw0 + 16, lr, lk);
    }
}

// ============ HGT aggregate: 4-edge chunked gather of kv[src], joint softmax, per-type partials ============
__global__ __launch_bounds__(256) void hgt_agg_k(const u16* __restrict__ kvb,
    const u16* __restrict__ qtb, const float* __restrict__ prel,
    const int* __restrict__ coff, const int* __restrict__ csrc,
    u16* __restrict__ pb)
{
    int gid = blockIdx.x*256 + threadIdx.x;
    int node = gid >> 6, lane = gid & 63;
    int hh = lane >> 4;
    float a0[3], a1[3];
    float dsum = 0.f;
    #pragma unroll
    for (int t = 0; t < 3; ++t) {
        a0[t] = 0.f; a1[t] = 0.f;
        float ph = prel[t*4 + hh] * 0.17677669529663689f;  // 1/sqrt(32)
        float2 qv = bf2x(*(const unsigned*)&qtb[(size_t)t*ND + (size_t)node*128 + lane*2]);
        const int* cs = csrc + (size_t)t*EE;
        int beg = coff[t*(NN+1) + node], end = coff[t*(NN+1) + node + 1];
        int e = beg;
        for (; e + 4 <= end; e += 4) {
            int sA = cs[e], sB = cs[e+1], sC = cs[e+2], sD = cs[e+3];
            size_t rA = (size_t)sA*256 + lane*2, rB = (size_t)sB*256 + lane*2;
            size_t rC = (size_t)sC*256 + lane*2, rD = (size_t)sD*256 + lane*2;
            unsigned kA = *(const unsigned*)&kvb[rA], kB = *(const unsigned*)&kvb[rB];
            unsigned kC = *(const unsigned*)&kvb[rC], kD = *(const unsigned*)&kvb[rD];
            unsigned vA = *(const unsigned*)&kvb[rA+128], vB = *(const unsigned*)&kvb[rB+128];
            unsigned vC = *(const unsigned*)&kvb[rC+128], vD = *(const unsigned*)&kvb[rD+128];
            float2 k2A = bf2x(kA), k2B = bf2x(kB), k2C = bf2x(kC), k2D = bf2x(kD);
            float scA = qv.x*k2A.x + qv.y*k2A.y;
            float scB = qv.x*k2B.x + qv.y*k2B.y;
            float scC = qv.x*k2C.x + qv.y*k2C.y;
            float scD = qv.x*k2D.x + qv.y*k2D.y;
            #pragma unroll
            for (int o = 1; o < 16; o <<= 1){
                scA += __shfl_xor(scA, o); scB += __shfl_xor(scB, o);
                scC += __shfl_xor(scC, o); scD += __shfl_xor(scD, o);
            }
            float eA = expf(scA*ph), eB = expf(scB*ph), eC = expf(scC*ph), eD = expf(scD*ph);
            float2 v2A = bf2x(vA), v2B = bf2x(vB), v2C = bf2x(vC), v2D = bf2x(vD);
            dsum += eA + eB + eC + eD;
            a0[t] += eA*v2A.x + eB*v2B.x + eC*v2C.x + eD*v2D.x;
            a1[t] += eA*v2A.y + eB*v2B.y + eC*v2C.y + eD*v2D.y;
        }
        for (; e < end; ++e) {
            int s = cs[e];
            size_t ro = (size_t)s*256 + lane*2;
            float2 kv = bf2x(*(const unsigned*)&kvb[ro]);
            float sc = qv.x*kv.x + qv.y*kv.y;
            #pragma unroll
            for (int o = 1; o < 16; o <<= 1) sc += __shfl_xor(sc, o);
            float ex = expf(sc * ph);
            float2 vx = bf2x(*(const unsigned*)&kvb[ro + 128]);
            dsum += ex; a0[t] += ex*vx.x; a1[t] += ex*vx.y;
        }
    }
    float inv = 1.f/(dsum + 1e-16f);
    size_t o = (size_t)node*128 + lane*2;
    #pragma unroll
    for (int t = 0; t < 3; ++t)
        *(unsigned*)&pb[(size_t)t*ND + o] = cvt2(a0[t]*inv, a1[t]*inv);
}

// ============ final: Σ_t partial_t@M_t, gelu, @Wo + residual/rmsnorm + inject + FiLM ============
// LDS-staged weights; 2-tile; vectorized row-major epilogue via per-wave tb.
__global__ __launch_bounds__(256, 2) void final_k(const u16* __restrict__ pb,
    const u16* __restrict__ wpmrel, const u16* __restrict__ wpo, const float* __restrict__ bo,
    const u16* __restrict__ x2b, const float* __restrict__ skipp, const float* __restrict__ scale,
    const float* __restrict__ xemb, const u16* __restrict__ wpinj, const float* __restrict__ injb,
    const float* __restrict__ gbuf, const int* __restrict__ bszp,
    float* __restrict__ out)
{
    __shared__ __align__(16) u16 wl[128*WLP];
    __shared__ __align__(16) u16 tb[4][16][TBW];
    const int tid = threadIdx.x, wave = tid>>6, lane = tid&63, lr = lane&15, lk = lane>>4;
    const int rw0 = blockIdx.x*128 + wave*32;
    const int rw1 = rw0 + 16;
    // ---- agg_pre = Σ_t partial_t @ M_t (2 tiles, LDS-staged M_t) ----
    f32x4 acc0[8], acc1[8];
    #pragma unroll
    for (int i = 0; i < 8; ++i){ acc0[i] = (f32x4){0.f,0.f,0.f,0.f}; acc1[i] = (f32x4){0.f,0.f,0.f,0.f}; }
    for (int t = 0; t < 3; ++t){
        if (t) __syncthreads();
        stage_w(wpmrel + t*16384, wl, tid);
        __syncthreads();
        bf8_t a0[4], a1[4];
        load_af16(pb + (size_t)t*ND, rw0 + lr, lk, a0);
        load_af16(pb + (size_t)t*ND, rw1 + lr, lk, a1);
        mfma_l2_acc(a0, a1, wl, lr, lk, acc0, acc1);
    }
    // ---- gelu -> tb -> bf16 A-frags (sequential tiles through one tb) ----
    bf8_t ga0[4], ga1[4];
    acc_to_tb_gelu(tb[wave], acc0, lr, lk);
    tb_frags(tb[wave], lr, lk, ga0);
    acc_to_tb_gelu(tb[wave], acc1, lr, lk);
    tb_frags(tb[wave], lr, lk, ga1);
    // ---- Wo GEMM ----
    __syncthreads();
    stage_w(wpo, wl, tid);
    __syncthreads();
    mfma_l2(ga0, ga1, wl, lr, lk, acc0, acc1);
    bf8_t hw0[4], hw1[4];
    acc_to_tb(tb[wave], acc0, lr, lk, bo);
    tb_rows(tb[wave], lr, lk, hw0);
    acc_to_tb(tb[wave], acc1, lr, lk, bo);
    tb_rows(tb[wave], lr, lk, hw1);
    // ---- inject GEMM ----
    bf8_t e0[4], e1[4];
    load_af32(xemb, rw0 + lr, lk, e0);
    load_af32(xemb, rw1 + lr, lk, e1);
    __syncthreads();
    stage_w(wpinj, wl, tid);
    __syncthreads();
    mfma_l2(e0, e1, wl, lr, lk, acc0, acc1);
    bf8_t in0[4], in1[4];
    acc_to_tb(tb[wave], acc0, lr, lk, injb);
    tb_rows(tb[wave], lr, lk, in0);
    acc_to_tb(tb[wave], acc1, lr, lk, injb);
    tb_rows(tb[wave], lr, lk, in1);
    // ---- vectorized row-major epilogue ----
    const float sig = 1.f/(1.f + expf(-skipp[0]));
    const int cpb = NN / *bszp;
    float4 sca = *(const float4*)&scale[lr*8];
    float4 scb = *(const float4*)&scale[lr*8 + 4];
    #pragma unroll
    for (int tile = 0; tile < 2; ++tile){
        const bf8_t* hw = tile ? hw1 : hw0;
        const bf8_t* in = tile ? in1 : in0;
        int rwb = tile ? rw1 : rw0;
        #pragma unroll
        for (int c = 0; c < 4; ++c){
            int row = rwb + c*4 + lk;
            bf8_t x8 = *(const bf8_t*)(x2b + (size_t)row*128 + lr*8);
            float x[8], v[8];
            float ssl = 0.f;
            #pragma unroll
            for (int j = 0; j < 8; ++j){
                x[j] = bf2f((u16)x8[j]);
                float h = bf2f((u16)hw[c][j]);
                v[j] = sig*h + (1.f - sig)*x[j];
                ssl += v[j]*v[j];
            }
            ssl += __shfl_xor(ssl, 1); ssl += __shfl_xor(ssl, 2);
            ssl += __shfl_xor(ssl, 4); ssl += __shfl_xor(ssl, 8);
            float rq = rsqrtf(ssl*(1.f/128.f) + 1e-6f);
            const float* gr = gbuf + (row / cpb)*256;
            float4 g0 = *(const float4*)&gr[lr*8];
            float4 g1 = *(const float4*)&gr[lr*8 + 4];
            float4 b0 = *(const float4*)&gr[128 + lr*8];
            float4 b1 = *(const float4*)&gr[128 + lr*8 + 4];
            float4 oA, oB;
            #pragma unroll
            for (int j = 0; j < 8; ++j){
                float scj = (j < 4) ? ((const float*)&sca)[j] : ((const float*)&scb)[j-4];
                float y = lrelu(x[j] + scj*v[j]*rq);
                float hf = y + bf2f((u16)in[c][j]);
                float gj = (j < 4) ? ((const float*)&g0)[j] : ((const float*)&g1)[j-4];
                float bj = (j < 4) ? ((const float*)&b0)[j] : ((const float*)&b1)[j-4];
                float ov = (1.f + gj)*hf + bj;
                if (j < 4) ((float*)&oA)[j] = ov; else ((float*)&oB)[j-4] = ov;
            }
            *(float4*)(out + (size_t)row*128 + lr*8)     = oA;
            *(float4*)(out + (size_t)row*128 + lr*8 + 4) = oB;
        }
    }
}

// ================= CSR build =================
__global__ __launch_bounds__(256) void hist_k(const int* __restrict__ ei, int* __restrict__ cnt){
    int gid = blockIdx.x*256 + threadIdx.x;
    int t = gid / EE, e = gid - t*EE;
    int d = ei[t*2*EE + EE + e];
    atomicAdd(&cnt[t*NN + d], 1);
}
__global__ __launch_bounds__(256) void scan1_k(const int* __restrict__ cnt, int* __restrict__ off, int* __restrict__ parts){
    __shared__ int sums[256];
    int b = blockIdx.x; int t = b >> 6; int base = (b & 63) * 1024;
    int tid = threadIdx.x;
    int v[4]; int tsum = 0;
    int gbase = t*NN + base + tid*4;
    #pragma unroll
    for (int i = 0; i < 4; ++i){ v[i] = cnt[gbase+i]; tsum += v[i]; }
    sums[tid] = tsum; __syncthreads();
    for (int ofs = 1; ofs < 256; ofs <<= 1) {
        int a = (tid >= ofs) ? sums[tid-ofs] : 0;
        __syncthreads();
        sums[tid] += a;
        __syncthreads();
    }
    int run = sums[tid] - tsum;
    int obase = t*(NN+1) + base + tid*4;
    #pragma unroll
    for (int i = 0; i < 4; ++i){ off[obase+i] = run; run += v[i]; }
    if (tid == 255) parts[b] = sums[255];
}
__global__ void scan2_k(int* parts){
    if (threadIdx.x == 0 && blockIdx.x == 0) {
        for (int t = 0; t < 3; ++t) {
            int run = 0;
            for (int i = 0; i < 64; ++i) { int b = t*64+i; int v = parts[b]; parts[b] = run; run += v; }
        }
    }
}
__global__ __launch_bounds__(256) void scan3_k(int* __restrict__ off, const int* __restrict__ parts){
    int b = blockIdx.x; int t = b >> 6; int base = (b & 63) * 1024;
    int add = parts[b];
    int idx = t*(NN+1) + base + threadIdx.x*4;
    #pragma unroll
    for (int i = 0; i < 4; ++i) off[idx+i] += add;
    if (threadIdx.x == 0 && (b & 63) == 0) off[t*(NN+1) + NN] = EE;
}
__global__ __launch_bounds__(256) void scatter_k(const int* __restrict__ ei, const int* __restrict__ off,
                                                 int* __restrict__ cur, int* __restrict__ out){
    int gid = blockIdx.x*256 + threadIdx.x;
    int t = gid / EE, e = gid - t*EE;
    int s = ei[t*2*EE + e];
    int d = ei[t*2*EE + EE + e];
    int p = atomicAdd(&cur[t*NN + d], 1);
    out[t*EE + off[t*(NN+1)+d] + p] = s;
}

// ============ fused GAT aggregate (4-edge chunked bf16 h gather) + bias + rmsnorm residual ============
template<int XF32>
__global__ __launch_bounds__(256) void gat_aggres_k(const u16* __restrict__ hb,
    const float* __restrict__ alsb, const float* __restrict__ aldb,
    const int* __restrict__ coff, const int* __restrict__ csrc,
    const float* __restrict__ bias3, const float* __restrict__ xoldf, const u16* __restrict__ xoldb,
    const float* __restrict__ scale, u16* __restrict__ outb)
{
    int gid = blockIdx.x*256 + threadIdx.x;
    int node = gid >> 6, lane = gid & 63;
    int g = lane >> 4;
    float a0 = 0.f, a1 = 0.f;
    for (int t = 0; t < 3; ++t) {
        const u16* h = hb + (size_t)t*ND;
        const float* als = alsb + (size_t)t*NN*4;
        float ad = aldb[(size_t)t*NN*4 + node*4 + g];
        float aself = als[node*4 + g];
        const int* cs = csrc + (size_t)t*EE;
        int beg = coff[t*(NN+1) + node], end = coff[t*(NN+1) + node + 1];
        float ex = expf(lrelu(aself + ad));
        float dsum = ex;
        float2 hv = bf2x(*(const unsigned*)&h[(size_t)node*128 + lane*2]);
        float s0 = ex*hv.x, s1 = ex*hv.y;
        int e = beg;
        for (; e + 4 <= end; e += 4) {
            int sA = cs[e], sB = cs[e+1], sC = cs[e+2], sD = cs[e+3];
            unsigned hA = *(const unsigned*)&h[(size_t)sA*128 + lane*2];
            unsigned hB = *(const unsigned*)&h[(size_t)sB*128 + lane*2];
            unsigned hC = *(const unsigned*)&h[(size_t)sC*128 + lane*2];
            unsigned hD = *(const unsigned*)&h[(size_t)sD*128 + lane*2];
            float aA = als[sA*4+g], aB = als[sB*4+g], aC = als[sC*4+g], aD = als[sD*4+g];
            float eA = expf(lrelu(aA + ad)), eB = expf(lrelu(aB + ad));
            float eC = expf(lrelu(aC + ad)), eD = expf(lrelu(aD + ad));
            float2 wA = bf2x(hA), wB = bf2x(hB), wC = bf2x(hC), wD = bf2x(hD);
            dsum += eA + eB + eC + eD;
            s0 += eA*wA.x + eB*wB.x + eC*wC.x + eD*wD.x;
            s1 += eA*wA.y + eB*wB.y + eC*wC.y + eD*wD.y;
        }
        for (; e < end; ++e) {
            int s = cs[e];
            unsigned hp = *(const unsigned*)&h[(size_t)s*128 + lane*2];
            float av = als[s*4 + g];
            float exx = expf(lrelu(av + ad));
            float2 hw = bf2x(hp);
            dsum += exx; s0 += exx*hw.x; s1 += exx*hw.y;
        }
        float inv = 1.f/(dsum + 1e-16f);
        a0 += s0*inv; a1 += s1*inv;
    }
    int c0 = lane*2;
    a0 += bias3[c0]   + bias3[128+c0]   + bias3[256+c0];
    a1 += bias3[c0+1] + bias3[128+c0+1] + bias3[256+c0+1];
    float ssum = a0*a0 + a1*a1;
    #pragma unroll
    for (int o = 1; o < 64; o <<= 1) ssum += __shfl_xor(ssum, o);
    float r = rsqrtf(ssum*(1.f/128.f) + 1e-6f);
    size_t off = (size_t)node*128 + c0;
    float2 xo;
    if (XF32) xo = *(const float2*)&xoldf[off];
    else      xo = bf2x(*(const unsigned*)&xoldb[off]);
    float y0 = lrelu(xo.x + scale[c0]*a0*r);
    float y1 = lrelu(xo.y + scale[c0+1]*a1*r);
    *(unsigned*)&outb[off] = cvt2(y0, y1);
}

// ============ FiLM small MLP ============
__global__ __launch_bounds__(256) void film_k(const float* __restrict__ z,
    const float* __restrict__ W1, const float* __restrict__ b1,
    const float* __restrict__ W2, const float* __restrict__ b2,
    float* __restrict__ gb)
{
    __shared__ float zr[128];
    __shared__ float g1[256];
    int r = blockIdx.x, tid = threadIdx.x;
    if (tid < 128) zr[tid] = z[r*128 + tid];
    __syncthreads();
    float s = b1[tid];
    for (int k = 0; k < 128; ++k) s += zr[k]*W1[k*256 + tid];
    g1[tid] = gelu_exact(s);
    __syncthreads();
    float s2 = b2[tid];
    for (int k = 0; k < 256; ++k) s2 += g1[k]*W2[k*256 + tid];
    gb[r*256 + tid] = 0.1f*tanhf(s2);
}

// ================= launch =================
extern "C" void kernel_launch(void* const* d_in, const int* in_sizes, int n_in,
                              void* d_out, int out_size, void* d_ws, size_t ws_size,
                              hipStream_t stream)
{
    const float* x_cell = (const float*)d_in[0];
    const float* z_h    = (const float*)d_in[1];
    const float* x_emb  = (const float*)d_in[2];
    const int*   eidx   = (const int*)d_in[3];
    const int*   bszp   = (const int*)d_in[4];
    const float* g1W  = (const float*)d_in[5];
    const float* g1as = (const float*)d_in[6];
    const float* g1ad = (const float*)d_in[7];
    const float* g1b  = (const float*)d_in[8];
    const float* g2W  = (const float*)d_in[9];
    const float* g2as = (const float*)d_in[10];
    const float* g2ad = (const float*)d_in[11];
    const float* g2b  = (const float*)d_in[12];
    const float* n1s  = (const float*)d_in[13];
    const float* n2s  = (const float*)d_in[14];
    const float* n3s  = (const float*)d_in[15];
    const float* Wk   = (const float*)d_in[16];
    const float* bk   = (const float*)d_in[17];
    const float* Wq   = (const float*)d_in[18];
    const float* bq   = (const float*)d_in[19];
    const float* Wv   = (const float*)d_in[20];
    const float* bv   = (const float*)d_in[21];
    const float* arel = (const float*)d_in[22];
    const float* mrel = (const float*)d_in[23];
    const float* prel = (const float*)d_in[24];
    const float* Wo   = (const float*)d_in[25];
    const float* bo   = (const float*)d_in[26];
    const float* skipp= (const float*)d_in[27];
    const float* injW = (const float*)d_in[28];
    const float* injb = (const float*)d_in[29];
    const float* fW1  = (const float*)d_in[30];
    const float* fb1  = (const float*)d_in[31];
    const float* fW2  = (const float*)d_in[32];
    const float* fb2  = (const float*)d_in[33];

    // ---- workspace layout ----
    u16* wp   = (u16*)d_ws;                   // 17*16384 u16
    u16* wpa  = wp + (size_t)17*16384;        // 6*2048 u16
    u16* x1b  = wpa + 6*2048;                 // ND u16
    u16* x2b  = x1b + ND;                     // ND u16
    u16* kvb  = x2b + ND;                     // 2*ND u16 (k|v interleaved, row 256)
    u16* pb   = kvb + 2*ND;                   // 3*ND u16 (HGT per-type partials)
    u16* hb   = pb + 3*ND;                    // 3*ND u16 (GAT h; reused as qtb)
    float* alsb = (float*)(hb + 3*ND);        // 3*NN*4 f32
    float* aldb = alsb + (size_t)3*NN*4;      // 3*NN*4 f32
    float* gbuf = aldb + (size_t)3*NN*4;      // 32*256 f32
    int* coff   = (int*)(gbuf + 32*256);      // 3*(NN+1)
    int* csrc   = coff + 3*(NN+1);            // 3*EE
    int* tmpc   = csrc + 3*EE;                // 3*NN
    int* parts  = tmpc + 3*NN;                // 256

    u16* qtb = hb;                            // reuse (h dead after GAT2 aggres)
    float* outp = (float*)d_out;

    const u16* wpg1 = wp;
    const u16* wpg2 = wp + (size_t)3*16384;
    const u16* wpk  = wp + (size_t)6*16384;
    const u16* wpq  = wp + (size_t)7*16384;
    const u16* wpv  = wp + (size_t)8*16384;
    const u16* wpo  = wp + (size_t)9*16384;
    const u16* wpinj= wp + (size_t)10*16384;
    const u16* wparel = wp + (size_t)11*16384;
    const u16* wpmrel = wp + (size_t)14*16384;

    // ---- weight pre-pack ----
    wpack_k<<<18, 256, 0, stream>>>(g1W, g2W, Wk, Wq, Wv, Wo, injW, arel, mrel,
                                    g1as, g1ad, g2as, g2ad, wp, wpa);

    // ---- CSR build (shared by GAT1, GAT2, HGT) ----
    hipMemsetAsync(tmpc, 0, 3*NN*sizeof(int), stream);
    hist_k<<<3*EE/256, 256, 0, stream>>>(eidx, tmpc);
    scan1_k<<<192, 256, 0, stream>>>(tmpc, coff, parts);
    scan2_k<<<1, 64, 0, stream>>>(parts);
    scan3_k<<<192, 256, 0, stream>>>(coff, parts);
    hipMemsetAsync(tmpc, 0, 3*NN*sizeof(int), stream);
    scatter_k<<<3*EE/256, 256, 0, stream>>>(eidx, coff, tmpc, csrc);

    // ---- FiLM small MLP ----
    int B = in_sizes[1] / 128;
    film_k<<<B, 256, 0, stream>>>(z_h, fW1, fb1, fW2, fb2, gbuf);

    // ---- GAT layer 1 ----
    gat_gemm3_k<1><<<512, 256, 0, stream>>>(x_cell, nullptr, wpg1, wpa, hb, alsb, aldb);
    gat_aggres_k<1><<<16384, 256, 0, stream>>>(hb, alsb, aldb, coff, csrc, g1b, x_cell, nullptr, n1s, x1b);

    // ---- GAT layer 2 ----
    gat_gemm3_k<0><<<512, 256, 0, stream>>>(nullptr, x1b, wpg2, wpa + 3*2048, hb, alsb, aldb);
    gat_aggres_k<0><<<16384, 256, 0, stream>>>(hb, alsb, aldb, coff, csrc, g2b, nullptr, x1b, n2s, x2b);

    // ---- HGT ----
    hgt_proj_k<<<512, 256, 0, stream>>>(x2b, wpk, wpq, wpv, wparel,
                                        bk, bq, bv, kvb, qtb);
    hgt_agg_k<<<16384, 256, 0, stream>>>(kvb, qtb, prel, coff, csrc, pb);

    // ---- final: Σ partial@M + gelu + Wo + residual + inject + FiLM ----
    final_k<<<512, 256, 0, stream>>>(pb, wpmrel, wpo, bo, x2b, skipp, n3s,
                                     x_emb, wpinj, injb, gbuf, bszp, outp);
}